// Round 1
// baseline (900.659 us; speedup 1.0000x reference)
//
#include <hip/hip_runtime.h>
#include <stdint.h>

#define HID 256
#define BATCH 16384
#define SEQ 20
#define OUTF 214
#define BM 64
#define NBLK (BATCH/BM)   // 256 blocks, one per CU
#define ROWE 264          // h row stride in bf16 elems (256 + 8 pad -> 2-way-max LDS bank aliasing)

typedef __attribute__((ext_vector_type(8))) short short8;
typedef __attribute__((ext_vector_type(4))) float f32x4;

#define MFMA(a,b,c) __builtin_amdgcn_mfma_f32_16x16x32_bf16((a),(b),(c),0,0,0)

__device__ __forceinline__ unsigned short f2bf(float f) {
    unsigned int u = __builtin_bit_cast(unsigned int, f);
    u += 0x7FFFu + ((u >> 16) & 1u);   // RNE
    return (unsigned short)(u >> 16);
}
__device__ __forceinline__ float sigm(float x)     { return __fdividef(1.0f, 1.0f + __expf(-x)); }
__device__ __forceinline__ float tanhfast(float x) { return 1.0f - __fdividef(2.0f, __expf(2.0f*x) + 1.0f); }

// ---------------- prep: pack weights into MFMA fragment-linear layout ----------------
// frag layout for a [Ntiles][Ktiles] matrix of 16x32 tiles: element (n,k) lives at
// short index (((n>>4)*KT + (k>>5))*64 + ((n&15) | (((k>>3)&3)<<4)))*8 + (k&7)
__global__ __launch_bounds__(256) void prep_kernel(
    const float* __restrict__ W_proj, const float* __restrict__ W_ih,
    const float* __restrict__ W_hh,  const float* __restrict__ b_ih,
    const float* __restrict__ b_hh,  const float* __restrict__ W_tech,
    const float* __restrict__ b_tech, const float* __restrict__ W_phase,
    const float* __restrict__ b_phase, const float* __restrict__ W_time,
    const float* __restrict__ b_time,
    unsigned short* __restrict__ Wc, unsigned short* __restrict__ Wi,
    unsigned short* __restrict__ Wo, unsigned short* __restrict__ Wp,
    float* __restrict__ b_comb, float* __restrict__ b_out)
{
    const int n = blockIdx.x;    // 0..1023 (gate row)
    const int k = threadIdx.x;   // 0..255
    const int lane = (n & 15) | (((k >> 3) & 3) << 4);
    const int e  = k & 7;
    const int tn = n >> 4;
    {
        float wi = W_ih[n*HID + k], wh = W_hh[n*HID + k];
        int idx = ((tn*8 + (k>>5))*64 + lane)*8 + e;
        Wi[idx] = f2bf(wi);
        Wc[idx] = f2bf(wi + wh);
    }
    if (n < 224) {   // out projection: [tech(200) | phase(13) | time(1) | zero-pad]
        float v = 0.0f;
        if (n < 200)       v = W_tech[n*HID + k];
        else if (n < 213)  v = W_phase[(n-200)*HID + k];
        else if (n == 213) v = W_time[k];
        int idx = ((tn*8 + (k>>5))*64 + lane)*8 + e;
        Wo[idx] = f2bf(v);
    }
    if (n < 256 && k < 128) {  // W_proj padded K 100->128
        float v = (k < 100) ? W_proj[n*100 + k] : 0.0f;
        int idx = ((tn*4 + (k>>5))*64 + lane)*8 + e;
        Wp[idx] = f2bf(v);
    }
    if (n < 4) b_comb[n*256 + k] = b_ih[n*256 + k] + b_hh[n*256 + k];
    if (n == 4 && k < 224) {
        float v = 0.0f;
        if (k < 200)       v = b_tech[k];
        else if (k < 213)  v = b_phase[k-200];
        else if (k == 213) v = b_time[0];
        b_out[k] = v;
    }
}

// ---------------- main persistent LSTM kernel ----------------
// 256 blocks x 512 threads (8 waves). Block owns 64 batch rows for all 20 steps.
// Wave w owns hidden slice j in [w*32, w*32+32). Gates GEMM computes D[n][m]
// (A = W fragment-packed from L2, B = h from LDS), so the LSTM elementwise and
// the h write-back are register-local per wave.
__global__ __launch_bounds__(512, 2) void lstm_kernel(
    const float* __restrict__ noise, const float* __restrict__ b_proj,
    const unsigned short* __restrict__ Wc, const unsigned short* __restrict__ Wi,
    const unsigned short* __restrict__ Wo_g, const unsigned short* __restrict__ Wp,
    const float* __restrict__ b_comb, const float* __restrict__ b_out,
    float* __restrict__ out)
{
    __shared__ __attribute__((aligned(16))) unsigned short hbuf[BM * ROWE];   // 33.0 KiB
    __shared__ __attribute__((aligned(16))) unsigned short wo[14*8*64*8];     // 112 KiB

    const int tid  = threadIdx.x;
    const int w    = tid >> 6;
    const int lane = tid & 63;
    const int lr   = lane & 15;    // D col (= batch m within tile) / A row within tile
    const int lq   = lane >> 4;    // k-slot group; D row group
    const int blk  = blockIdx.x;

    { // stage W_out fragments -> LDS (contiguous copy, 7168 x 16B)
        const uint4* src = (const uint4*)Wo_g;
        uint4* dst = (uint4*)wo;
        #pragma unroll
        for (int i = 0; i < 14; ++i) dst[tid + i*512] = src[tid + i*512];
    }
    { // stage noise -> hbuf as bf16 (cols 0..99), zero-pad 100..127
        const float* nsrc = noise + (size_t)blk * BM * 100;
        for (int i = tid; i < BM*100; i += 512) {
            int m = i / 100; int kk = i - m*100;
            hbuf[m*ROWE + kk] = f2bf(nsrc[i]);
        }
        for (int i = tid; i < BM*28; i += 512) {
            int m = i / 28; int kk = i - m*28;
            hbuf[m*ROWE + 100 + kk] = 0;
        }
    }

    const int jb0 = w*32;
    // biases in registers (16B-aligned vector loads)
    f32x4 bi[2][4];
    #pragma unroll
    for (int jt = 0; jt < 2; ++jt)
        #pragma unroll
        for (int g = 0; g < 4; ++g)
            bi[jt][g] = *(const f32x4*)&b_comb[g*256 + jb0 + jt*16 + lq*4];
    f32x4 bp[2];
    #pragma unroll
    for (int jt = 0; jt < 2; ++jt)
        bp[jt] = *(const f32x4*)&b_proj[jb0 + jt*16 + lq*4];
    f32x4 bo0 = *(const f32x4*)&b_out[w*16 + lq*4];
    f32x4 bo1 = {0.f,0.f,0.f,0.f};
    if (w < 6) bo1 = *(const f32x4*)&b_out[(8+w)*16 + lq*4];

    f32x4 c_[2][4];
    #pragma unroll
    for (int jt = 0; jt < 2; ++jt)
        #pragma unroll
        for (int mt = 0; mt < 4; ++mt) c_[jt][mt] = f32x4{0.f,0.f,0.f,0.f};

    __syncthreads();

    // ---- step -1: x0 = noise @ W_proj.T + b_proj  (K padded to 128), written into hbuf
    {
        f32x4 acc[2][4];
        #pragma unroll
        for (int jt = 0; jt < 2; ++jt)
            #pragma unroll
            for (int mt = 0; mt < 4; ++mt) acc[jt][mt] = f32x4{0.f,0.f,0.f,0.f};
        #pragma unroll
        for (int kk = 0; kk < 4; ++kk) {
            short8 b[4];
            #pragma unroll
            for (int mt = 0; mt < 4; ++mt)
                b[mt] = *(const short8*)&hbuf[(mt*16+lr)*ROWE + kk*32 + lq*8];
            #pragma unroll
            for (int jt = 0; jt < 2; ++jt) {
                short8 a = *(const short8*)&Wp[(((w*2+jt)*4 + kk)*64 + lane)*8];
                #pragma unroll
                for (int mt = 0; mt < 4; ++mt)
                    acc[jt][mt] = MFMA(a, b[mt], acc[jt][mt]);
            }
        }
        __syncthreads();  // all reads of noise staging done
        #pragma unroll
        for (int jt = 0; jt < 2; ++jt) {
            const int jb = jb0 + jt*16 + lq*4;
            #pragma unroll
            for (int mt = 0; mt < 4; ++mt) {
                f32x4 v = acc[jt][mt] + bp[jt];
                unsigned int p0 = (unsigned int)f2bf(v.x) | ((unsigned int)f2bf(v.y) << 16);
                unsigned int p1 = (unsigned int)f2bf(v.z) | ((unsigned int)f2bf(v.w) << 16);
                uint2 pk; pk.x = p0; pk.y = p1;
                *(uint2*)&hbuf[(mt*16+lr)*ROWE + jb] = pk;
            }
        }
    }
    __syncthreads();

    // ---- 20 LSTM steps ----
    for (int t = 0; t < SEQ; ++t) {
        const unsigned short* __restrict__ Wf = (t == 0) ? Wi : Wc;  // step0: x0@W_ih.T; else h@(W_ih+W_hh).T
        f32x4 acc[2][4][4];   // [jt][gate][mt]
        #pragma unroll
        for (int jt = 0; jt < 2; ++jt)
            #pragma unroll
            for (int g = 0; g < 4; ++g)
                #pragma unroll
                for (int mt = 0; mt < 4; ++mt) acc[jt][g][mt] = f32x4{0.f,0.f,0.f,0.f};

        #pragma unroll
        for (int kk = 0; kk < 8; ++kk) {
            short8 b[4];
            #pragma unroll
            for (int mt = 0; mt < 4; ++mt)
                b[mt] = *(const short8*)&hbuf[(mt*16+lr)*ROWE + kk*32 + lq*8];
            #pragma unroll
            for (int jt = 0; jt < 2; ++jt) {
                #pragma unroll
                for (int g = 0; g < 4; ++g) {
                    short8 a = *(const short8*)&Wf[(((g*16 + w*2 + jt)*8 + kk)*64 + lane)*8];
                    #pragma unroll
                    for (int mt = 0; mt < 4; ++mt)
                        acc[jt][g][mt] = MFMA(a, b[mt], acc[jt][g][mt]);
                }
            }
        }
        __syncthreads();   // all gate reads of hbuf complete -> safe to overwrite h in place

        #pragma unroll
        for (int jt = 0; jt < 2; ++jt) {
            const int jb = jb0 + jt*16 + lq*4;
            #pragma unroll
            for (int mt = 0; mt < 4; ++mt) {
                f32x4 xi = acc[jt][0][mt] + bi[jt][0];
                f32x4 xf = acc[jt][1][mt] + bi[jt][1];
                f32x4 xg = acc[jt][2][mt] + bi[jt][2];
                f32x4 xo = acc[jt][3][mt] + bi[jt][3];
                f32x4 cc = c_[jt][mt];
                float hh[4];
                #pragma unroll
                for (int r = 0; r < 4; ++r) {
                    float iv = sigm(xi[r]);
                    float fv = sigm(xf[r]);
                    float gv = tanhfast(xg[r]);
                    float ov = sigm(xo[r]);
                    float cn = fv*cc[r] + iv*gv;
                    cc[r] = cn;
                    hh[r] = ov * tanhfast(cn);
                }
                c_[jt][mt] = cc;
                unsigned int p0 = (unsigned int)f2bf(hh[0]) | ((unsigned int)f2bf(hh[1]) << 16);
                unsigned int p1 = (unsigned int)f2bf(hh[2]) | ((unsigned int)f2bf(hh[3]) << 16);
                uint2 pk; pk.x = p0; pk.y = p1;
                *(uint2*)&hbuf[(mt*16+lr)*ROWE + jb] = pk;
            }
        }
        __syncthreads();   // h_new complete

        // ---- output projection: out_t = h_new @ W_out.T + b_out  (wave w -> tiles w, 8+w)
        {
            f32x4 oa0[4], oa1[4];
            #pragma unroll
            for (int mt = 0; mt < 4; ++mt) { oa0[mt] = f32x4{0.f,0.f,0.f,0.f}; oa1[mt] = f32x4{0.f,0.f,0.f,0.f}; }
            #pragma unroll
            for (int kk = 0; kk < 8; ++kk) {
                short8 b[4];
                #pragma unroll
                for (int mt = 0; mt < 4; ++mt)
                    b[mt] = *(const short8*)&hbuf[(mt*16+lr)*ROWE + kk*32 + lq*8];
                short8 a0 = *(const short8*)&wo[((w*8 + kk)*64 + lane)*8];
                #pragma unroll
                for (int mt = 0; mt < 4; ++mt) oa0[mt] = MFMA(a0, b[mt], oa0[mt]);
                if (w < 6) {
                    short8 a1 = *(const short8*)&wo[(((8+w)*8 + kk)*64 + lane)*8];
                    #pragma unroll
                    for (int mt = 0; mt < 4; ++mt) oa1[mt] = MFMA(a1, b[mt], oa1[mt]);
                }
            }
            float* outt = out + (size_t)t * BATCH * OUTF + (size_t)blk * BM * OUTF;
            const int col0 = w*16 + lq*4;   // tiles 0..7 -> cols 0..127, always in range
            #pragma unroll
            for (int mt = 0; mt < 4; ++mt) {
                int row = mt*16 + lr;
                f32x4 v = oa0[mt] + bo0;
                float2 lo; lo.x = v.x; lo.y = v.y;
                float2 hi; hi.x = v.z; hi.y = v.w;
                *(float2*)&outt[(size_t)row*OUTF + col0]     = lo;
                *(float2*)&outt[(size_t)row*OUTF + col0 + 2] = hi;
            }
            if (w < 6) {
                const int col1 = (8+w)*16 + lq*4;   // cols 128..223 (valid < 214)
                #pragma unroll
                for (int mt = 0; mt < 4; ++mt) {
                    int row = mt*16 + lr;
                    f32x4 v = oa1[mt] + bo1;
                    if (col1 + 3 < OUTF) {
                        float2 lo; lo.x = v.x; lo.y = v.y;
                        float2 hi; hi.x = v.z; hi.y = v.w;
                        *(float2*)&outt[(size_t)row*OUTF + col1]     = lo;
                        *(float2*)&outt[(size_t)row*OUTF + col1 + 2] = hi;
                    } else if (col1 < OUTF) {
                        // col1 == 212: n=212 (phase), n=213 (timing, ReLU)
                        float2 lo; lo.x = v.x; lo.y = (v.y > 0.f) ? v.y : 0.f;
                        *(float2*)&outt[(size_t)row*OUTF + col1] = lo;
                    }
                }
            }
        }
        // no barrier needed here: next iteration's first barrier orders the in-place h update
    }
}

extern "C" void kernel_launch(void* const* d_in, const int* in_sizes, int n_in,
                              void* d_out, int out_size, void* d_ws, size_t ws_size,
                              hipStream_t stream) {
    const float* noise   = (const float*)d_in[0];
    const float* W_proj  = (const float*)d_in[1];
    const float* b_proj  = (const float*)d_in[2];
    const float* W_ih    = (const float*)d_in[3];
    const float* W_hh    = (const float*)d_in[4];
    const float* b_ih    = (const float*)d_in[5];
    const float* b_hh    = (const float*)d_in[6];
    const float* W_tech  = (const float*)d_in[7];
    const float* b_tech  = (const float*)d_in[8];
    const float* W_phase = (const float*)d_in[9];
    const float* b_phase = (const float*)d_in[10];
    const float* W_time  = (const float*)d_in[11];
    const float* b_time  = (const float*)d_in[12];

    char* ws = (char*)d_ws;
    unsigned short* Wc = (unsigned short*)(ws);            // 512 KiB: frag(W_ih + W_hh)
    unsigned short* Wi = (unsigned short*)(ws + 524288);   // 512 KiB: frag(W_ih)
    unsigned short* Wo = (unsigned short*)(ws + 1048576);  // 112 KiB: frag(W_out padded to 224)
    unsigned short* Wp = (unsigned short*)(ws + 1163264);  //  64 KiB: frag(W_proj padded K=128)
    float* b_comb = (float*)(ws + 1228800);                //   4 KiB
    float* b_out  = (float*)(ws + 1232896);                // 896 B

    prep_kernel<<<1024, 256, 0, stream>>>(W_proj, W_ih, W_hh, b_ih, b_hh,
                                          W_tech, b_tech, W_phase, b_phase, W_time, b_time,
                                          Wc, Wi, Wo, Wp, b_comb, b_out);
    lstm_kernel<<<NBLK, 512, 0, stream>>>(noise, b_proj, Wc, Wi, Wo, Wp, b_comb, b_out,
                                          (float*)d_out);
}